// Round 8
// baseline (9659.703 us; speedup 1.0000x reference)
//
#include <hip/hip_runtime.h>
#include <math.h>
#include <stdint.h>

#define STEPS 127
typedef unsigned int uint;
typedef unsigned short ushort;
typedef unsigned char uchar;

typedef __attribute__((ext_vector_type(8))) short short8;
typedef __attribute__((ext_vector_type(4))) float f32x4;

// ---------------- common device helpers ----------------
__device__ __forceinline__ void tfround(unsigned &x0, unsigned &x1, int r) {
  x0 += x1; x1 = (x1 << r) | (x1 >> (32 - r)); x1 ^= x0;
}
__device__ void threefry2x32(unsigned k0, unsigned k1, unsigned c0, unsigned c1,
                             unsigned &o0, unsigned &o1) {
  unsigned ks2 = k0 ^ k1 ^ 0x1BD11BDAu;
  unsigned x0 = c0 + k0, x1 = c1 + k1;
  tfround(x0,x1,13); tfround(x0,x1,15); tfround(x0,x1,26); tfround(x0,x1,6);
  x0 += k1; x1 += ks2 + 1u;
  tfround(x0,x1,17); tfround(x0,x1,29); tfround(x0,x1,16); tfround(x0,x1,24);
  x0 += ks2; x1 += k0 + 2u;
  tfround(x0,x1,13); tfround(x0,x1,15); tfround(x0,x1,26); tfround(x0,x1,6);
  x0 += k0; x1 += k1 + 3u;
  tfround(x0,x1,17); tfround(x0,x1,29); tfround(x0,x1,16); tfround(x0,x1,24);
  x0 += k1; x1 += ks2 + 4u;
  tfround(x0,x1,13); tfround(x0,x1,15); tfround(x0,x1,26); tfround(x0,x1,6);
  x0 += ks2; x1 += k0 + 5u;
  o0 = x0; o1 = x1;
}
__device__ __forceinline__ float gumbel_from_bits(unsigned b) {
  unsigned fb = (b >> 9) | 0x3F800000u;
  float f = __uint_as_float(fb) - 1.0f;
  const float tiny = 1.17549435e-38f;
  float u = fmaxf(tiny, f * (1.0f - tiny) + tiny);
  return -logf(-logf(u));
}
__device__ __forceinline__ ushort f2bf(float f) {
  unsigned u = __float_as_uint(f);
  unsigned r = (u + 0x7FFFu + ((u >> 16) & 1u)) >> 16;
  return (ushort)r;
}
__device__ __forceinline__ float bf2f(ushort s) { return __uint_as_float(((uint)s) << 16); }
__device__ __forceinline__ float bflo(uint w) { return __uint_as_float(w << 16); }
__device__ __forceinline__ float bfhi(uint w) { return __uint_as_float(w & 0xFFFF0000u); }

// ============ k1: gumbel + weight folds -> MFMA B-frag packed bf16 ============
// Wpk layout: slot = (t*24+jt)*13 + sub; sub 0-4 = Wq kt (K-ext: kt4 = W2), 5-8 = Wr, 9-12 = Whh.
// short index o = (slot*64 + lane)*8 + i ; element (j,k): j = jt*16+(lane&15), k = kt*32+(lane>>4)*8+i
__global__ void k1_folds(const float* msgW, const float* msgB, const float* Wih,
                         const float* Whh, float* g, ushort* Wpk, float* bm2G) {
  const int gtid = blockIdx.x * blockDim.x + threadIdx.x;
  const int GSZ = gridDim.x * blockDim.x;
  for (int idx = gtid; idx < 16256; idx += GSZ) {
    unsigned o0, o1; threefry2x32(0u, 42u, 0u, (unsigned)idx, o0, o1);
    g[idx] = gumbel_from_bits(o0 ^ o1);
  }
  for (int o = gtid; o < 319488; o += GSZ) {
    int slot = o >> 9; int rem = o & 511; int lane = rem >> 3; int i = rem & 7;
    int unit = slot / 13, sub = slot % 13;
    int tt = unit / 24, jt = unit % 24;
    int j = jt * 16 + (lane & 15);
    int mat = (sub < 5) ? 0 : (sub < 9 ? 1 : 2);
    int kt = (sub < 5) ? sub : (sub < 9 ? sub - 5 : sub - 9);
    int k = kt * 32 + (lane >> 4) * 8 + i;
    float val = 0.f;
    if (mat == 2) {
      val = Whh[(size_t)(tt * 384 + j) * 128 + k];
    } else {
      int col = -1;
      if (mat == 0) { if (k < 128) col = k; else if (k < 144) col = 256 + (k - 128); }
      else col = 128 + k;
      if (col >= 0) {
        const float* wih = Wih + (size_t)(tt * 384 + j) * 128;
        const float* mw = msgW + (size_t)tt * 128 * 272 + col;
        float acc = 0.f;
        for (int m = 0; m < 128; ++m) acc += wih[m] * mw[(size_t)m * 272];
        val = acc;
      }
    }
    Wpk[o] = f2bf(val);
  }
  for (int o = gtid; o < 768; o += GSZ) {
    int tt = o / 384, j = o % 384;
    const float* wih = Wih + (size_t)(tt * 384 + j) * 128;
    const float* mb = msgB + tt * 128;
    float acc = 0.f;
    for (int m = 0; m < 128; ++m) acc += wih[m] * mb[m];
    bm2G[o] = acc;
  }
}

// ============ k2: victim scan + perm + hv0 + CSR (sorted) + minMaxEnd ============
__global__ void k2_scan(const int* node_types, const int* esrc, const int* edst,
                        const float* enc_W, const float* enc_b, const float* g,
                        int* permG, ushort* hv0Row, int* rpG, uchar* colG, ushort* eidG,
                        int* miscG, float* out) {
  __shared__ int vict[127];
  __shared__ int permL[128];
  __shared__ int cnt[128];
  __shared__ int rp[129];
  __shared__ int cur[128];
  __shared__ uchar colS[2048];
  __shared__ ushort eidS[2048];
  const int tid = threadIdx.x;   // 128 threads
  // --- victim scan (wave 0), original ids, verified logic ---
  if (tid < 64) {
    int lane = tid;
    bool a0 = true, a1 = true;
    float lsum = 0.f;
    for (int s = 0; s < STEPS; ++s) {
      float c = logf(1.0f / (float)(128 - s));
      float g0 = a0 ? (c + g[s * 128 + lane]) : -INFINITY;
      float g1 = a1 ? (c + g[s * 128 + 64 + lane]) : -INFINITY;
      float bv; int bi;
      if (g0 >= g1) { bv = g0; bi = lane; } else { bv = g1; bi = lane + 64; }
      for (int off = 32; off > 0; off >>= 1) {
        float ov = __shfl_down(bv, off);
        int   oi = __shfl_down(bi, off);
        if (ov > bv || (ov == bv && oi < bi)) { bv = ov; bi = oi; }
      }
      int victim = __shfl(bi, 0);
      if (victim == lane) a0 = false;
      if (victim == lane + 64) a1 = false;
      lsum += c;
      if (lane == 0) {
        vict[s] = victim;
        out[128 + 127 - s] = (float)victim;
      }
    }
    unsigned long long m0 = __ballot(a0), m1 = __ballot(a1);
    int surv = m0 ? (__ffsll(m0) - 1) : (64 + __ffsll(m1) - 1);
    if (lane == 0) {
      out[128] = (float)surv; out[256] = lsum;
      permL[surv] = 0; miscG[1] = surv;
    }
  }
  __syncthreads();
  if (tid < 127) permL[vict[tid]] = 127 - tid;
  __syncthreads();
  if (tid < 128) permG[tid] = permL[tid];
  // hv0 (permuted, bf16 row layout)
  {
    int v_old = tid; int ty = node_types[v_old]; int vn = permL[v_old];
    for (int d = 0; d < 128; ++d)
      hv0Row[vn * 128 + d] = f2bf(enc_W[d * 32 + ty] + enc_b[d]);
  }
  // CSR on new ids
  if (tid < 128) { cnt[tid] = 0; cur[tid] = 0; }
  __syncthreads();
  for (int e = tid; e < 2048; e += 128) atomicAdd(&cnt[permL[edst[e]]], 1);
  __syncthreads();
  // prefix sum
  {
    __shared__ int pfs[128];
    if (tid < 128) pfs[tid] = cnt[tid];
    __syncthreads();
    for (int off = 1; off < 128; off <<= 1) {
      int add = 0;
      if (tid < 128 && tid >= off) add = pfs[tid - off];
      __syncthreads();
      if (tid < 128) pfs[tid] += add;
      __syncthreads();
    }
    if (tid == 0) rp[0] = 0;
    if (tid < 128) rp[tid + 1] = pfs[tid];
  }
  __syncthreads();
  int mme = 0x7FFFFFFF;
  for (int e = tid; e < 2048; e += 128) {
    int dn = permL[edst[e]], sn = permL[esrc[e]];
    int pos = atomicAdd(&cur[dn], 1);
    int q = rp[dn] + pos;
    colS[q] = (uchar)sn; eidS[q] = (ushort)e;
    int m = sn > dn ? sn : dn;
    if (m < mme) mme = m;
  }
  __syncthreads();
  // insertion sort each row ascending by col
  if (tid < 128) {
    int a = rp[tid], b = rp[tid + 1];
    for (int x = a + 1; x < b; ++x) {
      uchar c = colS[x]; ushort e = eidS[x];
      int y = x - 1;
      while (y >= a && colS[y] > c) { colS[y+1] = colS[y]; eidS[y+1] = eidS[y]; --y; }
      colS[y+1] = c; eidS[y+1] = e;
    }
  }
  __syncthreads();
  if (tid < 128) { rpG[tid] = rp[tid]; if (tid == 0) rpG[128] = rp[128]; }
  for (int q = tid; q < 2048; q += 128) { colG[q] = colS[q]; eidG[q] = eidS[q]; }
  // minMaxEnd reduce
  __shared__ int red[128];
  red[tid] = mme; __syncthreads();
  for (int off = 64; off > 0; off >>= 1) {
    if (tid < off) red[tid] = min(red[tid], red[tid + off]);
    __syncthreads();
  }
  if (tid == 0) miscG[0] = red[0];
}

// ============ k3: per-step deg + He fragments (permuted) ============
// HeF: per step s: 8 mt x 64 lanes x uint4 (kt=4 frag, quads>=2 pre-zeroed by memset)
__global__ void k3_steps(const int* rpG, const uchar* colG, const ushort* eidG,
                         const float* he, uchar* degG, ushort* HeF) {
  const int s = blockIdx.x;     // 127 blocks
  const int v = threadIdx.x;    // 128 threads
  int lim = 127 - s;
  int a = rpG[v], b = rpG[v + 1];
  float acc[16];
  #pragma unroll
  for (int k = 0; k < 16; ++k) acc[k] = 0.f;
  int deg = 0;
  for (int q = a; q < b; ++q) {
    int c = colG[q];
    if (c > lim) break;
    int e = eidG[q];
    const float* hr = he + (size_t)e * 16;
    #pragma unroll
    for (int k = 0; k < 16; ++k) acc[k] += hr[k];
    deg++;
  }
  degG[s * 128 + v] = (uchar)deg;
  int mt = v >> 4;
  #pragma unroll
  for (int k2 = 0; k2 < 16; ++k2) {
    int quad = k2 >> 3, i = k2 & 7;
    int lane = (v & 15) + 16 * quad;
    HeF[(size_t)((s * 8 + mt) * 64 + lane) * 8 + i] = f2bf(acc[k2]);
  }
}

// ============ k5: main loop — 1 block, 1024 threads, all-LDS, MFMA ============
struct MainP {
  const ushort* Wpk; const float* bm2G; const float* bih; const float* bhh;
  const ushort* hv0Row; const ushort* HeF; const uchar* degG;
  const int* rpG; const uchar* colG; const int* miscG;
  float* out;
};

__global__ __launch_bounds__(1024, 1) void k5_main(MainP p) {
  __shared__ ushort hvRow[16384];                 // [v][d] bf16
  __shared__ alignas(16) ushort hvA[16384];       // A-frag: ((v>>4)*4+(d>>5))*64 + (v&15)+16*((d>>3)&3), i=d&7
  __shared__ alignas(16) ushort sfrag[20480];     // A-frag K=160: ((mt*5+kt)*64+lane)*8+i
  __shared__ ushort gbuf[16384];                  // [32 vloc][512]: 0-255 rz-fused, 256-383 gni, 384-511 gnh
  __shared__ float biasI[768], biasH[768], biasM[768];
  __shared__ float degF[128];
  __shared__ uchar degU[128];
  __shared__ short rpL[129];
  __shared__ uchar colL[2048];
  __shared__ int minMaxEnd;

  const int tid = threadIdx.x;
  const int lane = tid & 63, wave = tid >> 6;
  const uint4* Wp4 = (const uint4*)p.Wpk;
  uint4* hvA4 = (uint4*)hvA;
  uint4* sfrag4 = (uint4*)sfrag;

  // ---- load static LDS ----
  if (tid < 129) rpL[tid] = (short)p.rpG[tid];
  for (int q = tid; q < 2048; q += 1024) colL[q] = p.colG[q];
  for (int o = tid; o < 768; o += 1024) {
    biasI[o] = p.bih[o]; biasH[o] = p.bhh[o]; biasM[o] = p.bm2G[o];
  }
  if (tid == 0) minMaxEnd = p.miscG[0];
  for (int o = tid; o < 8192; o += 1024)
    ((uint*)hvRow)[o] = ((const uint*)p.hv0Row)[o];
  __syncthreads();
  // build hvA from hvRow
  #pragma unroll
  for (int ii = 0; ii < 16; ++ii) {
    int e = tid + 1024 * ii;
    int v = e >> 7, d = e & 127;
    hvA[(((v >> 4) * 4 + (d >> 5)) * 64 + (v & 15) + 16 * ((d >> 3) & 3)) * 8 + (d & 7)] = hvRow[e];
  }

  // ---- load weights into VGPRs (B-fragments) ----
  int ujt[3], utt[3];
  uint4 wQ[3][5], wR[3][4], wH[3][4];
  #pragma unroll
  for (int uu = 0; uu < 3; ++uu) {
    int u = wave + 16 * uu;
    utt[uu] = u / 24; ujt[uu] = u % 24;
    int base = (utt[uu] * 24 + ujt[uu]) * 13;
    #pragma unroll
    for (int kt = 0; kt < 5; ++kt) wQ[uu][kt] = Wp4[(size_t)(base + kt) * 64 + lane];
    #pragma unroll
    for (int kt = 0; kt < 4; ++kt) {
      wR[uu][kt] = Wp4[(size_t)(base + 5 + kt) * 64 + lane];
      wH[uu][kt] = Wp4[(size_t)(base + 9 + kt) * 64 + lane];
    }
  }
  __syncthreads();

  // ---- main loop ----
  for (int s = 0; s < STEPS; ++s) {
    const int aliveN = 128 - s;
    const int Mact = (aliveN + 15) >> 4;
    const int Qact = (Mact + 1) >> 1;
    const int hasE = (127 - s) >= minMaxEnd;
    // step loads: deg row + He frags (kt=4 region of sfrag)
    if (tid < 128) { uchar d8 = p.degG[s * 128 + tid]; degU[tid] = d8; degF[tid] = (float)d8; }
    if (tid < 512) {
      int mt = tid >> 6, ln = tid & 63;
      sfrag4[(mt * 5 + 4) * 64 + ln] = ((const uint4*)p.HeF)[(size_t)(s * 8 + mt) * 64 + ln];
    }
    __syncthreads();

    for (int t = 0; t < 2; ++t) {
      // ---- gather S into sfrag (kt 0..3) ----
      {
        int v = tid >> 3, ch = tid & 7;
        if (v < aliveN) {
          int cntv = degU[v];
          int rp0 = rpL[v];
          float a[16];
          #pragma unroll
          for (int k = 0; k < 16; ++k) a[k] = 0.f;
          for (int q = 0; q < cntv; ++q) {
            int u = colL[rp0 + q];
            const uint* hw = (const uint*)&hvRow[u * 128 + ch * 16];
            #pragma unroll
            for (int w8 = 0; w8 < 8; ++w8) {
              uint w = hw[w8];
              a[2 * w8] += bflo(w);
              a[2 * w8 + 1] += bfhi(w);
            }
          }
          int mt = v >> 4;
          #pragma unroll
          for (int k2 = 0; k2 < 16; ++k2) {
            int d = ch * 16 + k2;
            int kt = d >> 5, qd = (d >> 3) & 3, i = d & 7;
            sfrag[((mt * 5 + kt) * 64 + (v & 15) + 16 * qd) * 8 + i] = f2bf(a[k2]);
          }
        }
      }
      __syncthreads();

      // ---- per-quarter MFMA + gates ----
      for (int Q = 0; Q < Qact; ++Q) {
        #pragma unroll
        for (int uu = 0; uu < 3; ++uu) {
          if (utt[uu] != t) continue;
          const int jt = ujt[uu];
          const bool isn = jt >= 16;
          #pragma unroll
          for (int mth = 0; mth < 2; ++mth) {
            int mt = Q * 2 + mth;
            if (mt >= Mact) continue;
            const uint4* sb = sfrag4 + (size_t)(mt * 5) * 64 + lane;
            const uint4* hb = hvA4 + (size_t)(mt * 4) * 64 + lane;
            f32x4 a1 = {0.f, 0.f, 0.f, 0.f};
            f32x4 a2 = {0.f, 0.f, 0.f, 0.f};
            f32x4 a3 = {0.f, 0.f, 0.f, 0.f};
            #pragma unroll
            for (int kt = 0; kt < 5; ++kt)
              a1 = __builtin_amdgcn_mfma_f32_16x16x32_bf16(
                     __builtin_bit_cast(short8, sb[kt * 64]),
                     __builtin_bit_cast(short8, wQ[uu][kt]), a1, 0, 0, 0);
            #pragma unroll
            for (int kt = 0; kt < 4; ++kt) {
              short8 hf = __builtin_bit_cast(short8, hb[kt * 64]);
              a2 = __builtin_amdgcn_mfma_f32_16x16x32_bf16(
                     hf, __builtin_bit_cast(short8, wR[uu][kt]), a2, 0, 0, 0);
              if (isn)
                a3 = __builtin_amdgcn_mfma_f32_16x16x32_bf16(
                       hf, __builtin_bit_cast(short8, wH[uu][kt]), a3, 0, 0, 0);
              else
                a1 = __builtin_amdgcn_mfma_f32_16x16x32_bf16(
                       hf, __builtin_bit_cast(short8, wH[uu][kt]), a1, 0, 0, 0);
            }
            // writeout (C/D: col=lane&15, row=(lane>>4)*4+reg — m89-verified)
            int n_ = lane & 15, quad = lane >> 4;
            int j = jt * 16 + n_;
            float bi = biasI[t * 384 + j], bm = biasM[t * 384 + j], bh = biasH[t * 384 + j];
            #pragma unroll
            for (int reg = 0; reg < 4; ++reg) {
              int row = quad * 4 + reg;
              int vg = mt * 16 + row;
              int vloc = (mt & 1) * 16 + row;
              float dg = degF[vg];
              float gi = a1[reg] + dg * a2[reg] + bi + dg * bm;
              if (!isn) {
                gbuf[vloc * 512 + j] = f2bf(gi + bh);
              } else {
                gbuf[vloc * 512 + 256 + (j - 256)] = f2bf(gi);
                gbuf[vloc * 512 + 384 + (j - 256)] = f2bf(a3[reg] + bh);
              }
            }
          }
        }
        __syncthreads();
        // gates for quarter Q
        #pragma unroll
        for (int ii = 0; ii < 4; ++ii) {
          int e = tid + 1024 * ii;
          int vloc = e >> 7, d = e & 127;
          int v = Q * 32 + vloc;
          if (v < aliveN) {
            float r_ = 1.f / (1.f + expf(-bf2f(gbuf[vloc * 512 + d])));
            float z  = 1.f / (1.f + expf(-bf2f(gbuf[vloc * 512 + 128 + d])));
            float nn = tanhf(bf2f(gbuf[vloc * 512 + 256 + d]) + r_ * bf2f(gbuf[vloc * 512 + 384 + d]));
            float old = bf2f(hvRow[v * 128 + d]);
            float nv = hasE ? (1.f - z) * nn + z * old : old;
            ushort nb = f2bf(nv);
            hvRow[v * 128 + d] = nb;
            hvA[(((v >> 4) * 4 + (d >> 5)) * 64 + (v & 15) + 16 * ((d >> 3) & 3)) * 8 + (d & 7)] = nb;
          }
        }
        __syncthreads();
      }
    }
  }
  // epilogue: survivor = new id 0
  if (tid < 128) p.out[tid] = bf2f(hvRow[tid]);
}

// ============ host ============
extern "C" void kernel_launch(void* const* d_in, const int* in_sizes, int n_in,
                              void* d_out, int out_size, void* d_ws, size_t ws_size,
                              hipStream_t stream) {
  (void)in_sizes; (void)n_in; (void)out_size; (void)ws_size;
  const int* node_types = (const int*)d_in[0];
  const int* esrc = (const int*)d_in[1];
  const int* edst = (const int*)d_in[2];
  const float* he = (const float*)d_in[3];
  const float* enc_W = (const float*)d_in[4];
  const float* enc_b = (const float*)d_in[5];
  const float* msg_W = (const float*)d_in[6];
  const float* msg_b = (const float*)d_in[7];
  const float* Wih = (const float*)d_in[8];
  const float* Whh = (const float*)d_in[9];
  const float* bih = (const float*)d_in[10];
  const float* bhh = (const float*)d_in[11];

  char* w = (char*)d_ws;
  auto take = [&](size_t n) { char* r = w; w += (n + 255) & ~(size_t)255; return r; };
  float* g       = (float*)take(16256 * 4);
  ushort* Wpk    = (ushort*)take((size_t)319488 * 2);
  float* bm2G    = (float*)take(768 * 4);
  int* permG     = (int*)take(128 * 4);
  ushort* hv0Row = (ushort*)take(16384 * 2);
  int* rpG       = (int*)take(129 * 4);
  uchar* colG    = (uchar*)take(2048);
  ushort* eidG   = (ushort*)take(2048 * 2);
  int* miscG     = (int*)take(256);
  uchar* degG    = (uchar*)take(127 * 128);
  ushort* HeF    = (ushort*)take((size_t)127 * 512 * 8 * 2);   // 127 steps x 8 mt x 64 lanes x 8 shorts

  (void)hipMemsetAsync(HeF, 0, (size_t)127 * 512 * 8 * 2, stream);

  hipLaunchKernelGGL(k1_folds, dim3(256), dim3(256), 0, stream,
                     msg_W, msg_b, Wih, Whh, g, Wpk, bm2G);
  hipLaunchKernelGGL(k2_scan, dim3(1), dim3(128), 0, stream,
                     node_types, esrc, edst, enc_W, enc_b, g,
                     permG, hv0Row, rpG, colG, eidG, miscG, (float*)d_out);
  hipLaunchKernelGGL(k3_steps, dim3(127), dim3(128), 0, stream,
                     rpG, colG, eidG, he, degG, HeF);
  MainP p;
  p.Wpk = Wpk; p.bm2G = bm2G; p.bih = bih; p.bhh = bhh;
  p.hv0Row = hv0Row; p.HeF = HeF; p.degG = degG;
  p.rpG = rpG; p.colG = colG; p.miscG = miscG;
  p.out = (float*)d_out;
  hipLaunchKernelGGL(k5_main, dim3(1), dim3(1024), 0, stream, p);
}

// Round 9
// 5184.978 us; speedup vs baseline: 1.8630x; 1.8630x over previous
//
#include <hip/hip_runtime.h>
#include <math.h>
#include <stdint.h>

#define STEPS 127
typedef unsigned int uint;
typedef unsigned short ushort;
typedef unsigned char uchar;

typedef __attribute__((ext_vector_type(8))) short short8;
typedef __attribute__((ext_vector_type(4))) float f32x4;

#define PADR 136   // padded shorts per hv/S row (136*2=272 B, 16B aligned, breaks bank stride)
#define GST 516    // gbuf row stride in shorts

// ---------------- common device helpers ----------------
__device__ __forceinline__ void tfround(unsigned &x0, unsigned &x1, int r) {
  x0 += x1; x1 = (x1 << r) | (x1 >> (32 - r)); x1 ^= x0;
}
__device__ void threefry2x32(unsigned k0, unsigned k1, unsigned c0, unsigned c1,
                             unsigned &o0, unsigned &o1) {
  unsigned ks2 = k0 ^ k1 ^ 0x1BD11BDAu;
  unsigned x0 = c0 + k0, x1 = c1 + k1;
  tfround(x0,x1,13); tfround(x0,x1,15); tfround(x0,x1,26); tfround(x0,x1,6);
  x0 += k1; x1 += ks2 + 1u;
  tfround(x0,x1,17); tfround(x0,x1,29); tfround(x0,x1,16); tfround(x0,x1,24);
  x0 += ks2; x1 += k0 + 2u;
  tfround(x0,x1,13); tfround(x0,x1,15); tfround(x0,x1,26); tfround(x0,x1,6);
  x0 += k0; x1 += k1 + 3u;
  tfround(x0,x1,17); tfround(x0,x1,29); tfround(x0,x1,16); tfround(x0,x1,24);
  x0 += k1; x1 += ks2 + 4u;
  tfround(x0,x1,13); tfround(x0,x1,15); tfround(x0,x1,26); tfround(x0,x1,6);
  x0 += ks2; x1 += k0 + 5u;
  o0 = x0; o1 = x1;
}
__device__ __forceinline__ float gumbel_from_bits(unsigned b) {
  unsigned fb = (b >> 9) | 0x3F800000u;
  float f = __uint_as_float(fb) - 1.0f;
  const float tiny = 1.17549435e-38f;
  float u = fmaxf(tiny, f * (1.0f - tiny) + tiny);
  return -logf(-logf(u));
}
__device__ __forceinline__ ushort f2bf(float f) {
  unsigned u = __float_as_uint(f);
  unsigned r = (u + 0x7FFFu + ((u >> 16) & 1u)) >> 16;
  return (ushort)r;
}
__device__ __forceinline__ float bf2f(ushort s) { return __uint_as_float(((uint)s) << 16); }
__device__ __forceinline__ float bflo(uint w) { return __uint_as_float(w << 16); }
__device__ __forceinline__ float bfhi(uint w) { return __uint_as_float(w & 0xFFFF0000u); }

// ============ k1: gumbel + weight folds -> MFMA B-frag packed bf16 ============
// Wpk layout (verified R8): slot = (t*24+jt)*13 + sub; sub 0-4 = Wq kt (kt4 = W2 K-ext),
// 5-8 = Wr, 9-12 = Whh. short o = (slot*64+lane)*8+i; j = jt*16+(lane&15), k = kt*32+(lane>>4)*8+i
__global__ void k1_folds(const float* msgW, const float* msgB, const float* Wih,
                         const float* Whh, float* g, ushort* Wpk, float* bm2G) {
  const int gtid = blockIdx.x * blockDim.x + threadIdx.x;
  const int GSZ = gridDim.x * blockDim.x;
  for (int idx = gtid; idx < 16256; idx += GSZ) {
    unsigned o0, o1; threefry2x32(0u, 42u, 0u, (unsigned)idx, o0, o1);
    g[idx] = gumbel_from_bits(o0 ^ o1);
  }
  for (int o = gtid; o < 319488; o += GSZ) {
    int slot = o >> 9; int rem = o & 511; int lane = rem >> 3; int i = rem & 7;
    int unit = slot / 13, sub = slot % 13;
    int tt = unit / 24, jt = unit % 24;
    int j = jt * 16 + (lane & 15);
    int mat = (sub < 5) ? 0 : (sub < 9 ? 1 : 2);
    int kt = (sub < 5) ? sub : (sub < 9 ? sub - 5 : sub - 9);
    int k = kt * 32 + (lane >> 4) * 8 + i;
    float val = 0.f;
    if (mat == 2) {
      val = Whh[(size_t)(tt * 384 + j) * 128 + k];
    } else {
      int col = -1;
      if (mat == 0) { if (k < 128) col = k; else if (k < 144) col = 256 + (k - 128); }
      else col = 128 + k;
      if (col >= 0) {
        const float* wih = Wih + (size_t)(tt * 384 + j) * 128;
        const float* mw = msgW + (size_t)tt * 128 * 272 + col;
        float acc = 0.f;
        for (int m = 0; m < 128; ++m) acc += wih[m] * mw[(size_t)m * 272];
        val = acc;
      }
    }
    Wpk[o] = f2bf(val);
  }
  for (int o = gtid; o < 768; o += GSZ) {
    int tt = o / 384, j = o % 384;
    const float* wih = Wih + (size_t)(tt * 384 + j) * 128;
    const float* mb = msgB + tt * 128;
    float acc = 0.f;
    for (int m = 0; m < 128; ++m) acc += wih[m] * mb[m];
    bm2G[o] = acc;
  }
}

// ============ k2: victim scan + perm + hv0 + CSR (sorted) + minMaxEnd ============
__global__ void k2_scan(const int* node_types, const int* esrc, const int* edst,
                        const float* enc_W, const float* enc_b, const float* g,
                        int* permG, ushort* hv0Row, int* rpG, uchar* colG, ushort* eidG,
                        int* miscG, float* out) {
  __shared__ int vict[127];
  __shared__ int permL[128];
  __shared__ int cnt[128];
  __shared__ int rp[129];
  __shared__ int cur[128];
  __shared__ uchar colS[2048];
  __shared__ ushort eidS[2048];
  const int tid = threadIdx.x;   // 128 threads
  if (tid < 64) {
    int lane = tid;
    bool a0 = true, a1 = true;
    float lsum = 0.f;
    for (int s = 0; s < STEPS; ++s) {
      float c = logf(1.0f / (float)(128 - s));
      float g0 = a0 ? (c + g[s * 128 + lane]) : -INFINITY;
      float g1 = a1 ? (c + g[s * 128 + 64 + lane]) : -INFINITY;
      float bv; int bi;
      if (g0 >= g1) { bv = g0; bi = lane; } else { bv = g1; bi = lane + 64; }
      for (int off = 32; off > 0; off >>= 1) {
        float ov = __shfl_down(bv, off);
        int   oi = __shfl_down(bi, off);
        if (ov > bv || (ov == bv && oi < bi)) { bv = ov; bi = oi; }
      }
      int victim = __shfl(bi, 0);
      if (victim == lane) a0 = false;
      if (victim == lane + 64) a1 = false;
      lsum += c;
      if (lane == 0) {
        vict[s] = victim;
        out[128 + 127 - s] = (float)victim;
      }
    }
    unsigned long long m0 = __ballot(a0), m1 = __ballot(a1);
    int surv = m0 ? (__ffsll(m0) - 1) : (64 + __ffsll(m1) - 1);
    if (lane == 0) {
      out[128] = (float)surv; out[256] = lsum;
      permL[surv] = 0; miscG[1] = surv;
    }
  }
  __syncthreads();
  if (tid < 127) permL[vict[tid]] = 127 - tid;
  __syncthreads();
  if (tid < 128) permG[tid] = permL[tid];
  {
    int v_old = tid; int ty = node_types[v_old]; int vn = permL[v_old];
    for (int d = 0; d < 128; ++d)
      hv0Row[vn * 128 + d] = f2bf(enc_W[d * 32 + ty] + enc_b[d]);
  }
  if (tid < 128) { cnt[tid] = 0; cur[tid] = 0; }
  __syncthreads();
  for (int e = tid; e < 2048; e += 128) atomicAdd(&cnt[permL[edst[e]]], 1);
  __syncthreads();
  {
    __shared__ int pfs[128];
    if (tid < 128) pfs[tid] = cnt[tid];
    __syncthreads();
    for (int off = 1; off < 128; off <<= 1) {
      int add = 0;
      if (tid < 128 && tid >= off) add = pfs[tid - off];
      __syncthreads();
      if (tid < 128) pfs[tid] += add;
      __syncthreads();
    }
    if (tid == 0) rp[0] = 0;
    if (tid < 128) rp[tid + 1] = pfs[tid];
  }
  __syncthreads();
  int mme = 0x7FFFFFFF;
  for (int e = tid; e < 2048; e += 128) {
    int dn = permL[edst[e]], sn = permL[esrc[e]];
    int pos = atomicAdd(&cur[dn], 1);
    int q = rp[dn] + pos;
    colS[q] = (uchar)sn; eidS[q] = (ushort)e;
    int m = sn > dn ? sn : dn;
    if (m < mme) mme = m;
  }
  __syncthreads();
  if (tid < 128) {
    int a = rp[tid], b = rp[tid + 1];
    for (int x = a + 1; x < b; ++x) {
      uchar c = colS[x]; ushort e = eidS[x];
      int y = x - 1;
      while (y >= a && colS[y] > c) { colS[y+1] = colS[y]; eidS[y+1] = eidS[y]; --y; }
      colS[y+1] = c; eidS[y+1] = e;
    }
  }
  __syncthreads();
  if (tid < 128) { rpG[tid] = rp[tid]; if (tid == 0) rpG[128] = rp[128]; }
  for (int q = tid; q < 2048; q += 128) { colG[q] = colS[q]; eidG[q] = eidS[q]; }
  __shared__ int red[128];
  red[tid] = mme; __syncthreads();
  for (int off = 64; off > 0; off >>= 1) {
    if (tid < off) red[tid] = min(red[tid], red[tid + off]);
    __syncthreads();
  }
  if (tid == 0) miscG[0] = red[0];
}

// ============ k3: per-step deg + He fragments (permuted, kt4-frag layout) ============
__global__ void k3_steps(const int* rpG, const uchar* colG, const ushort* eidG,
                         const float* he, uchar* degG, ushort* HeF) {
  const int s = blockIdx.x;     // 127 blocks
  const int v = threadIdx.x;    // 128 threads
  int lim = 127 - s;
  int a = rpG[v], b = rpG[v + 1];
  float acc[16];
  #pragma unroll
  for (int k = 0; k < 16; ++k) acc[k] = 0.f;
  int deg = 0;
  for (int q = a; q < b; ++q) {
    int c = colG[q];
    if (c > lim) break;
    int e = eidG[q];
    const float* hr = he + (size_t)e * 16;
    #pragma unroll
    for (int k = 0; k < 16; ++k) acc[k] += hr[k];
    deg++;
  }
  degG[s * 128 + v] = (uchar)deg;
  int mt = v >> 4;
  #pragma unroll
  for (int k2 = 0; k2 < 16; ++k2) {
    int quad = k2 >> 3, i = k2 & 7;
    int lane = (v & 15) + 16 * quad;
    HeF[(size_t)((s * 8 + mt) * 64 + lane) * 8 + i] = f2bf(acc[k2]);
  }
}

// ============ k5: main loop — 1 block, 512 threads (8 waves), all-LDS, MFMA ============
struct MainP {
  const ushort* Wpk; const float* bm2G; const float* bih; const float* bhh;
  const ushort* hv0Row; const ushort* HeF; const uchar* degG;
  const int* rpG; const uchar* colG; const int* miscG;
  float* out;
};

__device__ __forceinline__ short8 ldfrag(const ushort* rows, int m, int koff) {
  return __builtin_bit_cast(short8, *(const uint4*)&rows[m * PADR + koff]);
}

__global__ __launch_bounds__(512, 2) void k5_main(MainP p) {
  __shared__ ushort hvRow[128 * PADR];
  __shared__ ushort Srow[128 * PADR];
  __shared__ alignas(16) ushort HeL[8 * 512];
  __shared__ ushort gbuf[32 * GST];
  __shared__ float biasI[768], biasH[768], biasM[768];
  __shared__ float degF[128];
  __shared__ uchar degU[128];
  __shared__ short rpL[129];
  __shared__ uchar colL[2048];
  __shared__ int mmE;

  const int tid = threadIdx.x;
  const int lane = tid & 63, wave = tid >> 6;
  const uint4* Wp4 = (const uint4*)p.Wpk;

  // ---- static LDS ----
  if (tid < 129) rpL[tid] = (short)p.rpG[tid];
  for (int q = tid; q < 2048; q += 512) colL[q] = p.colG[q];
  for (int o = tid; o < 768; o += 512) {
    biasI[o] = p.bih[o]; biasH[o] = p.bhh[o]; biasM[o] = p.bm2G[o];
  }
  if (tid == 0) mmE = p.miscG[0];
  for (int o = tid; o < 16384; o += 512) {
    int v = o >> 7, d = o & 127;
    hvRow[v * PADR + d] = p.hv0Row[o];
  }
  __syncthreads();

  const int gv = tid >> 2, gch = tid & 3;   // gather mapping: 4 threads per node

  for (int s = 0; s < STEPS; ++s) {
    const int aliveN = 128 - s;
    const int Mact = (aliveN + 15) >> 4;
    const int hasE = (127 - s) >= mmE;
    if (tid < 128) { uchar d8 = p.degG[s * 128 + tid]; degU[tid] = d8; degF[tid] = (float)d8; }
    ((uint4*)HeL)[tid] = ((const uint4*)(p.HeF + (size_t)s * 4096))[tid];
    __syncthreads();

    for (int t = 0; t < 2; ++t) {
      // ---- prefetch this t's weight fragments into VGPRs (3 units/wave) ----
      uint4 wfr[39];
      #pragma unroll
      for (int uu = 0; uu < 3; ++uu) {
        #pragma unroll
        for (int f = 0; f < 13; ++f)
          wfr[uu * 13 + f] = Wp4[(size_t)(((t * 24 + 3 * wave + uu) * 13 + f) * 64 + lane)];
      }

      // ---- gather S (overlaps weight loads) ----
      if (gv < aliveN) {
        int cnt = degU[gv], rp0 = rpL[gv];
        float acc[32];
        #pragma unroll
        for (int k = 0; k < 32; ++k) acc[k] = 0.f;
        for (int q = 0; q < cnt; ++q) {
          int u = colL[rp0 + q];
          const uint4* src = (const uint4*)&hvRow[u * PADR + gch * 32];
          uint4 w0 = src[0], w1 = src[1], w2 = src[2], w3 = src[3];
          uint ws[16] = {w0.x,w0.y,w0.z,w0.w, w1.x,w1.y,w1.z,w1.w,
                         w2.x,w2.y,w2.z,w2.w, w3.x,w3.y,w3.z,w3.w};
          #pragma unroll
          for (int k = 0; k < 16; ++k) {
            acc[2*k]   += bflo(ws[k]);
            acc[2*k+1] += bfhi(ws[k]);
          }
        }
        uint4* dst = (uint4*)&Srow[gv * PADR + gch * 32];
        #pragma unroll
        for (int b4 = 0; b4 < 4; ++b4) {
          uint4 o;
          o.x = (uint)f2bf(acc[b4*8+0]) | ((uint)f2bf(acc[b4*8+1]) << 16);
          o.y = (uint)f2bf(acc[b4*8+2]) | ((uint)f2bf(acc[b4*8+3]) << 16);
          o.z = (uint)f2bf(acc[b4*8+4]) | ((uint)f2bf(acc[b4*8+5]) << 16);
          o.w = (uint)f2bf(acc[b4*8+6]) | ((uint)f2bf(acc[b4*8+7]) << 16);
          dst[b4] = o;
        }
      }
      __syncthreads();

      // ---- m-tile pair loop: MFMA -> gates ----
      for (int mtp = 0; mtp * 2 < Mact; ++mtp) {
        #pragma unroll
        for (int mh = 0; mh < 2; ++mh) {
          int mt = mtp * 2 + mh;
          if (mt < Mact) {
            int m = mt * 16 + (lane & 15);
            int kq = (lane >> 4) * 8;
            // hoist 9 A-frags, shared by all 3 units
            short8 s0 = ldfrag(Srow, m, kq);
            short8 s1 = ldfrag(Srow, m, 32 + kq);
            short8 s2 = ldfrag(Srow, m, 64 + kq);
            short8 s3 = ldfrag(Srow, m, 96 + kq);
            short8 sh = __builtin_bit_cast(short8, *(const uint4*)&HeL[(mt * 64 + lane) * 8]);
            short8 h0 = ldfrag(hvRow, m, kq);
            short8 h1 = ldfrag(hvRow, m, 32 + kq);
            short8 h2 = ldfrag(hvRow, m, 64 + kq);
            short8 h3 = ldfrag(hvRow, m, 96 + kq);
            #pragma unroll
            for (int uu = 0; uu < 3; ++uu) {
              const int jt = 3 * wave + uu;
              const bool isn = jt >= 16;
              f32x4 a1 = {0.f,0.f,0.f,0.f};
              f32x4 a2 = {0.f,0.f,0.f,0.f};
              f32x4 a3 = {0.f,0.f,0.f,0.f};
              a1 = __builtin_amdgcn_mfma_f32_16x16x32_bf16(s0, __builtin_bit_cast(short8, wfr[uu*13+0]), a1, 0,0,0);
              a1 = __builtin_amdgcn_mfma_f32_16x16x32_bf16(s1, __builtin_bit_cast(short8, wfr[uu*13+1]), a1, 0,0,0);
              a1 = __builtin_amdgcn_mfma_f32_16x16x32_bf16(s2, __builtin_bit_cast(short8, wfr[uu*13+2]), a1, 0,0,0);
              a1 = __builtin_amdgcn_mfma_f32_16x16x32_bf16(s3, __builtin_bit_cast(short8, wfr[uu*13+3]), a1, 0,0,0);
              a1 = __builtin_amdgcn_mfma_f32_16x16x32_bf16(sh, __builtin_bit_cast(short8, wfr[uu*13+4]), a1, 0,0,0);
              a2 = __builtin_amdgcn_mfma_f32_16x16x32_bf16(h0, __builtin_bit_cast(short8, wfr[uu*13+5]), a2, 0,0,0);
              a2 = __builtin_amdgcn_mfma_f32_16x16x32_bf16(h1, __builtin_bit_cast(short8, wfr[uu*13+6]), a2, 0,0,0);
              a2 = __builtin_amdgcn_mfma_f32_16x16x32_bf16(h2, __builtin_bit_cast(short8, wfr[uu*13+7]), a2, 0,0,0);
              a2 = __builtin_amdgcn_mfma_f32_16x16x32_bf16(h3, __builtin_bit_cast(short8, wfr[uu*13+8]), a2, 0,0,0);
              if (isn) {
                a3 = __builtin_amdgcn_mfma_f32_16x16x32_bf16(h0, __builtin_bit_cast(short8, wfr[uu*13+9]),  a3, 0,0,0);
                a3 = __builtin_amdgcn_mfma_f32_16x16x32_bf16(h1, __builtin_bit_cast(short8, wfr[uu*13+10]), a3, 0,0,0);
                a3 = __builtin_amdgcn_mfma_f32_16x16x32_bf16(h2, __builtin_bit_cast(short8, wfr[uu*13+11]), a3, 0,0,0);
                a3 = __builtin_amdgcn_mfma_f32_16x16x32_bf16(h3, __builtin_bit_cast(short8, wfr[uu*13+12]), a3, 0,0,0);
              } else {
                a1 = __builtin_amdgcn_mfma_f32_16x16x32_bf16(h0, __builtin_bit_cast(short8, wfr[uu*13+9]),  a1, 0,0,0);
                a1 = __builtin_amdgcn_mfma_f32_16x16x32_bf16(h1, __builtin_bit_cast(short8, wfr[uu*13+10]), a1, 0,0,0);
                a1 = __builtin_amdgcn_mfma_f32_16x16x32_bf16(h2, __builtin_bit_cast(short8, wfr[uu*13+11]), a1, 0,0,0);
                a1 = __builtin_amdgcn_mfma_f32_16x16x32_bf16(h3, __builtin_bit_cast(short8, wfr[uu*13+12]), a1, 0,0,0);
              }
              // writeout (C/D m89-verified: col=lane&15, row=(lane>>4)*4+reg)
              int n_ = lane & 15, quad = lane >> 4;
              int j = jt * 16 + n_;
              float bi = biasI[t * 384 + j], bm = biasM[t * 384 + j], bh = biasH[t * 384 + j];
              #pragma unroll
              for (int reg = 0; reg < 4; ++reg) {
                int row = quad * 4 + reg;
                int vg = mt * 16 + row;
                int vloc = (mt & 1) * 16 + row;
                float dg = degF[vg];
                float gi = a1[reg] + dg * a2[reg] + bi + dg * bm;
                if (!isn) {
                  gbuf[vloc * GST + j] = f2bf(gi + bh);
                } else {
                  gbuf[vloc * GST + 256 + (j - 256)] = f2bf(gi);
                  gbuf[vloc * GST + 384 + (j - 256)] = f2bf(a3[reg] + bh);
                }
              }
            }
          }
        }
        __syncthreads();
        // gates for the 32-node pair
        {
          int vbase = mtp * 32;
          #pragma unroll
          for (int ii = 0; ii < 8; ++ii) {
            int e = tid + 512 * ii;
            int vloc = e >> 7, d = e & 127;
            int v = vbase + vloc;
            if (v < aliveN) {
              float r_ = 1.f / (1.f + expf(-bf2f(gbuf[vloc * GST + d])));
              float z  = 1.f / (1.f + expf(-bf2f(gbuf[vloc * GST + 128 + d])));
              float nn = tanhf(bf2f(gbuf[vloc * GST + 256 + d]) + r_ * bf2f(gbuf[vloc * GST + 384 + d]));
              float old = bf2f(hvRow[v * PADR + d]);
              float nv = hasE ? (1.f - z) * nn + z * old : old;
              hvRow[v * PADR + d] = f2bf(nv);
            }
          }
        }
        __syncthreads();
      }
    }
  }
  // epilogue: survivor = new id 0
  if (tid < 128) p.out[tid] = bf2f(hvRow[tid]);
}

// ============ host ============
extern "C" void kernel_launch(void* const* d_in, const int* in_sizes, int n_in,
                              void* d_out, int out_size, void* d_ws, size_t ws_size,
                              hipStream_t stream) {
  (void)in_sizes; (void)n_in; (void)out_size; (void)ws_size;
  const int* node_types = (const int*)d_in[0];
  const int* esrc = (const int*)d_in[1];
  const int* edst = (const int*)d_in[2];
  const float* he = (const float*)d_in[3];
  const float* enc_W = (const float*)d_in[4];
  const float* enc_b = (const float*)d_in[5];
  const float* msg_W = (const float*)d_in[6];
  const float* msg_b = (const float*)d_in[7];
  const float* Wih = (const float*)d_in[8];
  const float* Whh = (const float*)d_in[9];
  const float* bih = (const float*)d_in[10];
  const float* bhh = (const float*)d_in[11];

  char* w = (char*)d_ws;
  auto take = [&](size_t n) { char* r = w; w += (n + 255) & ~(size_t)255; return r; };
  float* g       = (float*)take(16256 * 4);
  ushort* Wpk    = (ushort*)take((size_t)319488 * 2);
  float* bm2G    = (float*)take(768 * 4);
  int* permG     = (int*)take(128 * 4);
  ushort* hv0Row = (ushort*)take(16384 * 2);
  int* rpG       = (int*)take(129 * 4);
  uchar* colG    = (uchar*)take(2048);
  ushort* eidG   = (ushort*)take(2048 * 2);
  int* miscG     = (int*)take(256);
  uchar* degG    = (uchar*)take(127 * 128);
  ushort* HeF    = (ushort*)take((size_t)127 * 4096 * 2);

  (void)hipMemsetAsync(HeF, 0, (size_t)127 * 4096 * 2, stream);

  hipLaunchKernelGGL(k1_folds, dim3(256), dim3(256), 0, stream,
                     msg_W, msg_b, Wih, Whh, g, Wpk, bm2G);
  hipLaunchKernelGGL(k2_scan, dim3(1), dim3(128), 0, stream,
                     node_types, esrc, edst, enc_W, enc_b, g,
                     permG, hv0Row, rpG, colG, eidG, miscG, (float*)d_out);
  hipLaunchKernelGGL(k3_steps, dim3(127), dim3(128), 0, stream,
                     rpG, colG, eidG, he, degG, HeF);
  MainP p;
  p.Wpk = Wpk; p.bm2G = bm2G; p.bih = bih; p.bhh = bhh;
  p.hv0Row = hv0Row; p.HeF = HeF; p.degG = degG;
  p.rpG = rpG; p.colG = colG; p.miscG = miscG;
  p.out = (float*)d_out;
  hipLaunchKernelGGL(k5_main, dim3(1), dim3(512), 0, stream, p);
}